// Round 1
// baseline (843.511 us; speedup 1.0000x reference)
//
#include <hip/hip_runtime.h>
#include <hip/hip_bf16.h>
#include <math.h>

typedef __attribute__((ext_vector_type(8))) short   short8;
typedef __attribute__((ext_vector_type(4))) float   floatx4;

// ---------------- workspace layout (bytes) ----------------
// total ~90 MB
#define OFF_PRED_A   0ULL          // <= 8448 B  (32 x 33 x 2 f32 max)
#define OFF_PRED_B   16384ULL
#define OFF_PT       32768ULL      // 32 x 96 x 2 f32 = 24576 B
#define OFF_W2T      65536ULL      // 3 x (256 x 1024 bf16 = 524288 B)
#define OFF_F1       2097152ULL    // f1 bf16, max 1024x1024x2 = 2 MB
#define OFF_P2       4194304ULL    // partials2 f32, 4 x 1024 x 256 x 4 = 4 MB
#define OFF_X        8388608ULL    // x bf16, 12845056 B (same all levels)
#define OFF_P1       21233664ULL   // partials1 f32, 16 x 256 x 1024 x 4 = 16 MB
#define OFF_W1T      38010880ULL   // W1^T bf16, max 51380224 B

// ---------------- pred_init: (32,4096)@(4096,18)+b ----------------
__global__ __launch_bounds__(64) void pred_init_kernel(
    const float* __restrict__ lf, const float* __restrict__ Wt,
    const float* __restrict__ bt, float* __restrict__ pred)
{
    int blk = blockIdx.x;           // 32*18
    int j = blk % 18, b = blk / 18;
    int lane = threadIdx.x;
    const float* lfb = lf + (size_t)b * 4096;
    float acc = 0.f;
    for (int k = lane; k < 4096; k += 64)
        acc += lfb[k] * Wt[(size_t)k * 18 + j];
    #pragma unroll
    for (int off = 32; off >= 1; off >>= 1)
        acc += __shfl_xor(acc, off, 64);
    if (lane == 0) pred[b * 18 + j] = acc + bt[j];
}

// ---------------- generic transpose + f32->bf16: src (R,C) -> dst (C,R) ----------------
__global__ __launch_bounds__(256) void transpose_cvt(
    const float* __restrict__ src, __hip_bfloat16* __restrict__ dst, int R, int C)
{
    __shared__ float tile[32][33];
    int tx = threadIdx.x & 31, ty = threadIdx.x >> 5;  // 32 x 8
    int bx = blockIdx.x, by = blockIdx.y;
    #pragma unroll
    for (int k = 0; k < 4; ++k) {
        int r = by * 32 + ty + k * 8, c = bx * 32 + tx;
        tile[ty + k * 8][tx] = (r < R && c < C) ? src[(size_t)r * C + c] : 0.f;
    }
    __syncthreads();
    #pragma unroll
    for (int k = 0; k < 4; ++k) {
        int r = bx * 32 + ty + k * 8;   // output row = original col
        int c = by * 32 + tx;           // output col = original row
        if (r < C && c < R)
            dst[(size_t)r * R + c] = __float2bfloat16(tile[tx][ty + k * 8]);
    }
}

// ---------------- bilinear ROI sampling -> x (bf16, GEMM A layout) ----------------
__global__ __launch_bounds__(256) void sample_kernel(
    const float* __restrict__ feat, int H, int W, int lc,
    const float* __restrict__ predPrev, int nseg,
    __hip_bfloat16* __restrict__ x)
{
    int blk = blockIdx.x;            // 32*nseg
    int i = blk % nseg, b = blk / nseg;
    const float* pp = predPrev + (size_t)(b * (nseg + 1) + i) * 2;
    float x0 = pp[0], y0 = pp[1], x1 = pp[2], y1 = pp[3];
    float cx = 0.5f * (x0 + x1), cy = 0.5f * (y0 + y1);
    float dx = 0.5f * (x1 - x0), dy = 0.5f * (y1 - y0);
    int C = 1 << lc;
    int total = 49 << lc;
    size_t rowbase = (size_t)blk * total;
    const float* fb = feat + (size_t)b * H * W * C;
    for (int j = threadIdx.x; j < total; j += 256) {
        int pix = j >> lc;
        int c = j & (C - 1);
        int oy = pix / 7, ox = pix - oy * 7;
        float gx = (float)(ox - 3) * (1.f / 3.f);
        float gy = (float)(oy - 3) * (1.f / 3.f);
        float xs = dx * gx - dy * gy - cx;
        float ys = dy * gx + dx * gy - cy;
        float px = (xs + 1.f) * (float)(W - 1) * 0.5f;
        float py = (ys + 1.f) * (float)(H - 1) * 0.5f;
        float x0f = floorf(px), y0f = floorf(py);
        float wx = px - x0f, wy = py - y0f;
        int xi0 = (int)fminf(fmaxf(x0f,       0.f), (float)(W - 1));
        int xi1 = (int)fminf(fmaxf(x0f + 1.f, 0.f), (float)(W - 1));
        int yi0 = (int)fminf(fmaxf(y0f,       0.f), (float)(H - 1));
        int yi1 = (int)fminf(fmaxf(y0f + 1.f, 0.f), (float)(H - 1));
        float Ia = fb[((size_t)yi0 * W + xi0) * C + c];
        float Ib = fb[((size_t)yi1 * W + xi0) * C + c];
        float Ic = fb[((size_t)yi0 * W + xi1) * C + c];
        float Id = fb[((size_t)yi1 * W + xi1) * C + c];
        float va = (1.f - wx) * (1.f - wy) * Ia + (1.f - wx) * wy * Ib
                 + wx * (1.f - wy) * Ic + wx * wy * Id;
        x[rowbase + j] = __float2bfloat16(va);
    }
}

// ---------------- bf16 MFMA GEMM, split-K, no LDS ----------------
// A: (M,K) bf16 row-major.  Bt: (N,K) bf16 row-major (i.e. B transposed).
// P: (S,M,N) fp32 partials.  grid = (M/64, N/64, S); block = 64 (one wave).
// Wave tile 64x64 = 4x4 of mfma_f32_16x16x32_bf16.
__global__ __launch_bounds__(64) void gemm_mfma(
    const __hip_bfloat16* __restrict__ A, const __hip_bfloat16* __restrict__ Bt,
    float* __restrict__ P, int M, int N, int K, int slice)
{
    int lane = threadIdx.x;
    int lo = lane & 15, hi = lane >> 4;
    int mt = blockIdx.x, nt = blockIdx.y, s = blockIdx.z;
    const short* Ap = (const short*)A + (size_t)(mt * 64 + lo) * K + (size_t)s * slice + hi * 8;
    const short* Bp = (const short*)Bt + (size_t)(nt * 64 + lo) * K + (size_t)s * slice + hi * 8;

    floatx4 acc[4][4];
    #pragma unroll
    for (int a = 0; a < 4; ++a)
        #pragma unroll
        for (int b = 0; b < 4; ++b)
            acc[a][b] = floatx4{0.f, 0.f, 0.f, 0.f};

    short8 ca[4], cb[4], na[4], nb[4];
    int nch = slice >> 5;   // chunks of K=32

#define LDF(da, db, koff)                                                     \
    {                                                                         \
        _Pragma("unroll")                                                     \
        for (int q = 0; q < 4; ++q)                                           \
            da[q] = *(const short8*)(Ap + (size_t)q * 16 * K + (koff));       \
        _Pragma("unroll")                                                     \
        for (int q = 0; q < 4; ++q)                                           \
            db[q] = *(const short8*)(Bp + (size_t)q * 16 * K + (koff));       \
    }
#define MM(da, db)                                                            \
    {                                                                         \
        _Pragma("unroll")                                                     \
        for (int mi = 0; mi < 4; ++mi)                                        \
            _Pragma("unroll")                                                 \
            for (int ni = 0; ni < 4; ++ni)                                    \
                acc[mi][ni] = __builtin_amdgcn_mfma_f32_16x16x32_bf16(        \
                    da[mi], db[ni], acc[mi][ni], 0, 0, 0);                    \
    }

    LDF(ca, cb, 0)
    for (int c = 0; c + 1 < nch; c += 2) {
        LDF(na, nb, (c + 1) * 32)
        MM(ca, cb)
        if (c + 2 < nch) LDF(ca, cb, (c + 2) * 32)
        MM(na, nb)
    }
    if (nch & 1) MM(ca, cb)

    // epilogue: D row = hi*4 + r (within 16-tile), col = lo
    #pragma unroll
    for (int mi = 0; mi < 4; ++mi) {
        int row0 = mt * 64 + mi * 16 + hi * 4;
        #pragma unroll
        for (int ni = 0; ni < 4; ++ni) {
            int col = nt * 64 + ni * 16 + lo;
            #pragma unroll
            for (int r = 0; r < 4; ++r)
                P[((size_t)s * M + row0 + r) * N + col] = acc[mi][ni][r];
        }
    }
#undef LDF
#undef MM
}

// ---------------- reduce split-K partials + bias + tanh -> bf16 ----------------
__global__ __launch_bounds__(256) void reduce_tanh_kernel(
    const float* __restrict__ P1, const float* __restrict__ b1,
    __hip_bfloat16* __restrict__ f1, int M, int S)
{
    int e = blockIdx.x * 256 + threadIdx.x;   // e < M*1024 exactly
    int n = e & 1023;
    float v = b1[n];
    size_t stride = (size_t)M * 1024;
    for (int s = 0; s < S; ++s) v += P1[(size_t)s * stride + e];
    f1[e] = __float2bfloat16(tanhf(v));
}

// ---------------- head: tanh(f2_raw+b2) @ W3 + b3 + offset -> theta transform -> pt ----------------
__global__ __launch_bounds__(64) void gemm3pts_kernel(
    const float* __restrict__ P2, const float* __restrict__ b2,
    const float* __restrict__ W3, const float* __restrict__ b3,
    const float* __restrict__ predPrev, float* __restrict__ pt,
    int nseg, int lns, int M)
{
    int m = blockIdx.x;
    int lane = threadIdx.x;
    float acc[6] = {0.f, 0.f, 0.f, 0.f, 0.f, 0.f};
    #pragma unroll
    for (int q = 0; q < 4; ++q) {
        int k = lane + q * 64;
        float v = b2[k];
        #pragma unroll
        for (int s = 0; s < 4; ++s)
            v += P2[((size_t)s * M + m) * 256 + k];
        v = tanhf(v);
        const float* w = W3 + (size_t)k * 6;
        #pragma unroll
        for (int j = 0; j < 6; ++j) acc[j] += v * w[j];
    }
    #pragma unroll
    for (int j = 0; j < 6; ++j)
        #pragma unroll
        for (int off = 32; off >= 1; off >>= 1)
            acc[j] += __shfl_xor(acc[j], off, 64);
    if (lane == 0) {
        int i = m & (nseg - 1);
        int b = m >> lns;
        const float* pp = predPrev + (size_t)(b * (nseg + 1) + i) * 2;
        float x0 = pp[0], y0 = pp[1], x1 = pp[2], y1 = pp[3];
        float cx = 0.5f * (x0 + x1), cy = 0.5f * (y0 + y1);
        float dx = 0.5f * (x1 - x0), dy = 0.5f * (y1 - y0);
        float f[6];
        #pragma unroll
        for (int j = 0; j < 6; ++j) f[j] = acc[j] + b3[j];
        f[0] -= 1.f;
        f[4] += 1.f;
        int npnt = nseg * 3;
        size_t base = ((size_t)b * npnt + 3 * i) * 2;
        #pragma unroll
        for (int s = 0; s < 3; ++s) {
            float px = f[2 * s], py = f[2 * s + 1];
            pt[base + 2 * s]     = dx * px - dy * py + cx;
            pt[base + 2 * s + 1] = dy * px + dx * py + cy;
        }
    }
}

// ---------------- pair gather -> next pred (or final output *6) ----------------
__global__ __launch_bounds__(256) void pairs_kernel(
    const float* __restrict__ pt, float* __restrict__ outp, int nseg, int last)
{
    int npnt = nseg * 3;
    int Pn = 2 * nseg + 1;
    int idx = blockIdx.x * 256 + threadIdx.x;
    int total = 32 * Pn * 2;
    if (idx >= total) return;
    int c = idx & 1;
    int t = idx >> 1;
    int p = t % Pn, b = t / Pn;
    int i1, i2;
    if (p == 0) { i1 = i2 = 0; }
    else if (p >= Pn - 2) { i1 = i2 = npnt - (Pn - p); }
    else {
        int q = (p - 1) >> 1, r = (p - 1) & 1;
        int si = 1 + 3 * q;
        if (r == 0) { i1 = i2 = si; }
        else        { i1 = si + 1; i2 = si + 2; }
    }
    float v = 0.5f * (pt[((size_t)b * npnt + i1) * 2 + c] +
                      pt[((size_t)b * npnt + i2) * 2 + c]);
    if (last) {
        if (p < Pn - 1) outp[((size_t)b * (Pn - 1) + p) * 2 + c] = 6.f * v;
    } else {
        outp[((size_t)b * Pn + p) * 2 + c] = v;
    }
}

// ---------------- launch ----------------
extern "C" void kernel_launch(void* const* d_in, const int* in_sizes, int n_in,
                              void* d_out, int out_size, void* d_ws, size_t ws_size,
                              hipStream_t stream) {
    (void)in_sizes; (void)n_in; (void)out_size; (void)ws_size;
    const float* lf  = (const float*)d_in[0];
    const float* feats[3] = {(const float*)d_in[1], (const float*)d_in[2], (const float*)d_in[3]};
    const float* Wtr = (const float*)d_in[4];
    const float* btr = (const float*)d_in[5];

    char* ws = (char*)d_ws;
    float* predA = (float*)(ws + OFF_PRED_A);
    float* predB = (float*)(ws + OFF_PRED_B);
    float* ptbuf = (float*)(ws + OFF_PT);
    __hip_bfloat16* f1  = (__hip_bfloat16*)(ws + OFF_F1);
    float* P2           = (float*)(ws + OFF_P2);
    __hip_bfloat16* xb  = (__hip_bfloat16*)(ws + OFF_X);
    float* P1           = (float*)(ws + OFF_P1);
    __hip_bfloat16* W1T = (__hip_bfloat16*)(ws + OFF_W1T);

    // init pred (B=32, 9 pts)
    pred_init_kernel<<<dim3(32 * 18), 64, 0, stream>>>(lf, Wtr, btr, predA);

    // W2 transposes up-front (input-only dependency)
    for (int h = 0; h < 3; ++h) {
        __hip_bfloat16* w2t = (__hip_bfloat16*)(ws + OFF_W2T + (size_t)h * 524288);
        transpose_cvt<<<dim3(256 / 32, 1024 / 32), 256, 0, stream>>>(
            (const float*)d_in[8 + 6 * h], w2t, 1024, 256);
    }

    const int Hs[3]   = {28, 56, 112};
    const int lcs[3]  = {9, 8, 7};        // C = 512,256,128
    const int nsegs[3] = {8, 16, 32};
    const int lnss[3]  = {3, 4, 5};
    const int Ks[3]   = {25088, 12544, 6272};
    const int S1s[3]  = {16, 8, 4};       // slice = 1568 always

    float* predPrev = predA;
    float* predNext = predB;
    for (int h = 0; h < 3; ++h) {
        int H = Hs[h], W = Hs[h], lc = lcs[h];
        int nseg = nsegs[h], M = 32 * nseg, K = Ks[h], S1 = S1s[h];
        const float* W1 = (const float*)d_in[6 + 6 * h];
        const float* b1 = (const float*)d_in[7 + 6 * h];
        const float* b2 = (const float*)d_in[9 + 6 * h];
        const float* W3 = (const float*)d_in[10 + 6 * h];
        const float* b3 = (const float*)d_in[11 + 6 * h];
        __hip_bfloat16* w2t = (__hip_bfloat16*)(ws + OFF_W2T + (size_t)h * 524288);

        // W1 (K,1024) f32 -> W1T (1024,K) bf16
        transpose_cvt<<<dim3(1024 / 32, K / 32), 256, 0, stream>>>(W1, W1T, K, 1024);

        // ROI sampling -> x (M, K) bf16
        sample_kernel<<<dim3(32 * nseg), 256, 0, stream>>>(
            feats[h], H, W, lc, predPrev, nseg, xb);

        // GEMM1: x @ W1 -> partials (S1, M, 1024)
        gemm_mfma<<<dim3(M / 64, 1024 / 64, S1), 64, 0, stream>>>(
            xb, W1T, P1, M, 1024, K, K / S1);

        // reduce + b1 + tanh -> f1 bf16 (M,1024)
        reduce_tanh_kernel<<<dim3(M * 1024 / 256), 256, 0, stream>>>(P1, b1, f1, M, S1);

        // GEMM2: f1 @ W2 -> partials2 (4, M, 256)
        gemm_mfma<<<dim3(M / 64, 256 / 64, 4), 64, 0, stream>>>(
            f1, w2t, P2, M, 256, 1024, 256);

        // head + theta transform -> pt (B, 3*nseg, 2)
        gemm3pts_kernel<<<dim3(M), 64, 0, stream>>>(
            P2, b2, W3, b3, predPrev, ptbuf, nseg, lnss[h], M);

        // pair gather -> next pred / final out
        int Pn = 2 * nseg + 1;
        int last = (h == 2);
        float* dst = last ? (float*)d_out : predNext;
        pairs_kernel<<<dim3((32 * Pn * 2 + 255) / 256), 256, 0, stream>>>(
            ptbuf, dst, nseg, last);

        float* tmp = predPrev; predPrev = predNext; predNext = tmp;
    }
}

// Round 2
// 773.702 us; speedup vs baseline: 1.0902x; 1.0902x over previous
//
#include <hip/hip_runtime.h>
#include <hip/hip_bf16.h>
#include <math.h>

typedef __attribute__((ext_vector_type(8))) short   short8;
typedef __attribute__((ext_vector_type(4))) float   floatx4;

// ---------------- workspace layout (bytes) ----------------
#define OFF_PRED     0ULL          // 32*18*4 = 2304
#define OFF_PTA      16384ULL      // 32*96*2*4 = 24576
#define OFF_PTB      65536ULL      // 24576
#define OFF_W2T      131072ULL     // 3 * 524288
#define OFF_F1       2097152ULL    // max 1024*1024*2 = 2 MB
#define OFF_P2       4194304ULL    // 8*1024*256*4 = 8 MB
#define OFF_X        16777216ULL   // 12845056 B
#define OFF_P1       33554432ULL   // 28*256*1024*4 = 29360128 B
#define OFF_W1T      67108864ULL   // 89915392 B total (3 levels)

// ---------------- pair-gather helper (pred point from prev-level pt) ----------
__device__ inline void pair_idx(int p, int Pn, int npnt, int& i1, int& i2) {
    if (p == 0) { i1 = i2 = 0; }
    else if (p >= Pn - 2) { i1 = i2 = npnt - (Pn - p); }
    else {
        int q = (p - 1) >> 1, r = (p - 1) & 1;
        int si = 1 + 3 * q;
        if (r == 0) { i1 = i2 = si; } else { i1 = si + 1; i2 = si + 2; }
    }
}
// nsegP==0 -> read pred0 (B,9,2). else compute pair-mean from pt (B, 3*nsegP, 2)
__device__ inline float2 pred_point(const float* pred0, const float* pt,
                                    int nsegP, int b, int p) {
    if (nsegP == 0) {
        const float* q = pred0 + ((size_t)b * 9 + p) * 2;
        return float2{q[0], q[1]};
    }
    int npnt = nsegP * 3, Pn = 2 * nsegP + 1;
    int i1, i2; pair_idx(p, Pn, npnt, i1, i2);
    const float* a = pt + ((size_t)b * npnt + i1) * 2;
    const float* c = pt + ((size_t)b * npnt + i2) * 2;
    return float2{0.5f * (a[0] + c[0]), 0.5f * (a[1] + c[1])};
}

// ---------------- fused setup: all W1/W2 transposes + pred_init ----------------
struct SetupArgs {
    const float* W1s[3]; __hip_bfloat16* W1T[3]; int K[3];
    const float* W2s[3]; __hip_bfloat16* W2T[3];
    const float* lf; const float* Wt; const float* bt; float* pred;
};

__device__ inline void transpose_tile(const float* __restrict__ src,
                                      __hip_bfloat16* __restrict__ dst,
                                      int R, int C, int rowT, int colT,
                                      float (*tile)[33]) {
    int tx = threadIdx.x & 31, ty = threadIdx.x >> 5;  // 32 x 8
    int r0 = rowT * 32, c0 = colT * 32;
    #pragma unroll
    for (int k = 0; k < 4; ++k)
        tile[ty + k * 8][tx] = src[(size_t)(r0 + ty + k * 8) * C + c0 + tx];
    __syncthreads();
    #pragma unroll
    for (int k = 0; k < 4; ++k)
        dst[(size_t)(c0 + ty + k * 8) * R + r0 + tx] =
            __float2bfloat16(tile[tx][ty + k * 8]);
}

// grid: [0,43904) W1 tiles | [43904,44672) W2 tiles | [44672,44816) pred
__global__ __launch_bounds__(256) void setup_kernel(SetupArgs a) {
    __shared__ float tile[32][33];
    int id = blockIdx.x;
    if (id < 43904) {
        int h = (id < 25088) ? 0 : (id < 37632 ? 1 : 2);
        int base = (h == 0) ? 0 : (h == 1 ? 25088 : 37632);
        int l = id - base;
        transpose_tile(a.W1s[h], a.W1T[h], a.K[h], 1024, l >> 5, l & 31, tile);
    } else if (id < 44672) {
        int l = id - 43904;
        int h = l >> 8; int t = l & 255;
        transpose_tile(a.W2s[h], a.W2T[h], 1024, 256, t >> 3, t & 7, tile);
    } else {
        int l = id - 44672;
        int wave = threadIdx.x >> 6, lane = threadIdx.x & 63;
        int task = l * 4 + wave;         // < 576 = 32*18
        int j = task % 18, b = task / 18;
        const float* lfb = a.lf + (size_t)b * 4096;
        float acc = 0.f;
        for (int k = lane; k < 4096; k += 64)
            acc += lfb[k] * a.Wt[(size_t)k * 18 + j];
        #pragma unroll
        for (int off = 32; off >= 1; off >>= 1)
            acc += __shfl_xor(acc, off, 64);
        if (lane == 0) a.pred[b * 18 + j] = acc + a.bt[j];
    }
}

// ---------------- bilinear ROI sampling (LDS-cached coords, float4) ----------------
__global__ __launch_bounds__(256) void sample_kernel(
    const float* __restrict__ feat, int Wd, int lc,
    const float* __restrict__ pred0, const float* __restrict__ ptPrev, int nsegP,
    int lns, __hip_bfloat16* __restrict__ x)
{
    int nseg = 1 << lns;
    int blk = blockIdx.x;
    int i = blk & (nseg - 1), b = blk >> lns;
    float2 p0 = pred_point(pred0, ptPrev, nsegP, b, i);
    float2 p1 = pred_point(pred0, ptPrev, nsegP, b, i + 1);
    float cx = 0.5f * (p0.x + p1.x), cy = 0.5f * (p0.y + p1.y);
    float dx = 0.5f * (p1.x - p0.x), dy = 0.5f * (p1.y - p0.y);

    __shared__ float4 wv[49];
    __shared__ int4   ov[49];   // offsets in float4 units
    int t = threadIdx.x;
    int C = 1 << lc;
    if (t < 49) {
        int oy = t / 7, ox = t - oy * 7;
        float gx = (float)(ox - 3) * (1.f / 3.f);
        float gy = (float)(oy - 3) * (1.f / 3.f);
        float xs = dx * gx - dy * gy - cx;
        float ys = dy * gx + dx * gy - cy;
        float fW = (float)(Wd - 1);
        float px = (xs + 1.f) * fW * 0.5f;
        float py = (ys + 1.f) * fW * 0.5f;
        float x0f = floorf(px), y0f = floorf(py);
        float wx = px - x0f, wy = py - y0f;
        int xi0 = (int)fminf(fmaxf(x0f,       0.f), fW);
        int xi1 = (int)fminf(fmaxf(x0f + 1.f, 0.f), fW);
        int yi0 = (int)fminf(fmaxf(y0f,       0.f), fW);
        int yi1 = (int)fminf(fmaxf(y0f + 1.f, 0.f), fW);
        int c4 = C >> 2;
        ov[t] = int4{(yi0 * Wd + xi0) * c4, (yi1 * Wd + xi0) * c4,
                     (yi0 * Wd + xi1) * c4, (yi1 * Wd + xi1) * c4};
        wv[t] = float4{(1.f - wx) * (1.f - wy), (1.f - wx) * wy,
                       wx * (1.f - wy),         wx * wy};
    }
    __syncthreads();

    const float4* fb4 = (const float4*)(feat + (size_t)b * Wd * Wd * C);
    int c4 = 1 << (lc - 2);
    int total4 = 49 << (lc - 2);
    size_t rowbase = (size_t)blk * (49 << lc);
    for (int j = t; j < total4; j += 256) {
        int pix = j >> (lc - 2);
        int cc  = j & (c4 - 1);
        int4 o = ov[pix]; float4 w = wv[pix];
        float4 Ia = fb4[o.x + cc], Ib = fb4[o.y + cc];
        float4 Ic = fb4[o.z + cc], Id = fb4[o.w + cc];
        float4 v;
        v.x = w.x * Ia.x + w.y * Ib.x + w.z * Ic.x + w.w * Id.x;
        v.y = w.x * Ia.y + w.y * Ib.y + w.z * Ic.y + w.w * Id.y;
        v.z = w.x * Ia.z + w.y * Ib.z + w.z * Ic.z + w.w * Id.z;
        v.w = w.x * Ia.w + w.y * Ib.w + w.z * Ic.w + w.w * Id.w;
        __hip_bfloat16 h0 = __float2bfloat16(v.x), h1 = __float2bfloat16(v.y);
        __hip_bfloat16 h2 = __float2bfloat16(v.z), h3 = __float2bfloat16(v.w);
        ushort4 u = {*(unsigned short*)&h0, *(unsigned short*)&h1,
                     *(unsigned short*)&h2, *(unsigned short*)&h3};
        *(ushort4*)(x + rowbase + ((size_t)pix << lc) + cc * 4) = u;
    }
}

// ---------------- bf16 MFMA GEMM, split-K, 4 waves/block sharing A ----------------
// A: (M,K) bf16 row-major. Bt: (N,K) bf16 row-major. P: (S,M,N) fp32 partials.
// grid = (M/64, N/256, S); block = 256 (4 waves). wave w covers n-tile ntb*4+w.
__global__ __launch_bounds__(256) void gemm_mfma4(
    const __hip_bfloat16* __restrict__ A, const __hip_bfloat16* __restrict__ Bt,
    float* __restrict__ P, int M, int N, int K, int slice)
{
    int lane = threadIdx.x & 63;
    int wave = threadIdx.x >> 6;
    int lo = lane & 15, hi = lane >> 4;
    int mt = blockIdx.x, nt = blockIdx.y * 4 + wave, s = blockIdx.z;
    const short* Ap = (const short*)A + (size_t)(mt * 64 + lo) * K + (size_t)s * slice + hi * 8;
    const short* Bp = (const short*)Bt + (size_t)(nt * 64 + lo) * K + (size_t)s * slice + hi * 8;

    floatx4 acc[4][4];
    #pragma unroll
    for (int a = 0; a < 4; ++a)
        #pragma unroll
        for (int b = 0; b < 4; ++b)
            acc[a][b] = floatx4{0.f, 0.f, 0.f, 0.f};

    short8 ca[4], cb[4], na[4], nb[4];
    int nch = slice >> 5;

#define LDF(da, db, koff)                                                     \
    {                                                                         \
        _Pragma("unroll")                                                     \
        for (int q = 0; q < 4; ++q)                                           \
            da[q] = *(const short8*)(Ap + (size_t)q * 16 * K + (koff));       \
        _Pragma("unroll")                                                     \
        for (int q = 0; q < 4; ++q)                                           \
            db[q] = *(const short8*)(Bp + (size_t)q * 16 * K + (koff));       \
    }
#define MM(da, db)                                                            \
    {                                                                         \
        _Pragma("unroll")                                                     \
        for (int mi = 0; mi < 4; ++mi)                                        \
            _Pragma("unroll")                                                 \
            for (int ni = 0; ni < 4; ++ni)                                    \
                acc[mi][ni] = __builtin_amdgcn_mfma_f32_16x16x32_bf16(        \
                    da[mi], db[ni], acc[mi][ni], 0, 0, 0);                    \
    }

    LDF(ca, cb, 0)
    for (int c = 0; c + 1 < nch; c += 2) {
        LDF(na, nb, (c + 1) * 32)
        MM(ca, cb)
        if (c + 2 < nch) LDF(ca, cb, (c + 2) * 32)
        MM(na, nb)
    }
    if (nch & 1) MM(ca, cb)

    #pragma unroll
    for (int mi = 0; mi < 4; ++mi) {
        int row0 = mt * 64 + mi * 16 + hi * 4;
        #pragma unroll
        for (int ni = 0; ni < 4; ++ni) {
            int col = nt * 64 + ni * 16 + lo;
            #pragma unroll
            for (int r = 0; r < 4; ++r)
                P[((size_t)s * M + row0 + r) * N + col] = acc[mi][ni][r];
        }
    }
#undef LDF
#undef MM
}

// ---------------- reduce split-K partials + bias + tanh -> bf16 ----------------
__global__ __launch_bounds__(256) void reduce_tanh_kernel(
    const float* __restrict__ P1, const float* __restrict__ b1,
    __hip_bfloat16* __restrict__ f1, int M, int S)
{
    int e = blockIdx.x * 256 + threadIdx.x;
    int n = e & 1023;
    float v = b1[n];
    size_t stride = (size_t)M * 1024;
    for (int s = 0; s < S; ++s) v += P1[(size_t)s * stride + e];
    f1[e] = __float2bfloat16(tanhf(v));
}

// ---------------- head: reduce P2 + b2, tanh, @W3+b3+off, theta transform -> pt ----
__global__ __launch_bounds__(64) void gemm3pts_kernel(
    const float* __restrict__ P2, const float* __restrict__ b2,
    const float* __restrict__ W3, const float* __restrict__ b3,
    const float* __restrict__ pred0, const float* __restrict__ ptPrev, int nsegP,
    float* __restrict__ pt, int lns, int M)
{
    int m = blockIdx.x;
    int lane = threadIdx.x;
    int nseg = 1 << lns;
    float acc[6] = {0.f, 0.f, 0.f, 0.f, 0.f, 0.f};
    #pragma unroll
    for (int q = 0; q < 4; ++q) {
        int k = lane + q * 64;
        float v = b2[k];
        #pragma unroll
        for (int s = 0; s < 8; ++s)
            v += P2[((size_t)s * M + m) * 256 + k];
        v = tanhf(v);
        const float* w = W3 + (size_t)k * 6;
        #pragma unroll
        for (int j = 0; j < 6; ++j) acc[j] += v * w[j];
    }
    #pragma unroll
    for (int j = 0; j < 6; ++j)
        #pragma unroll
        for (int off = 32; off >= 1; off >>= 1)
            acc[j] += __shfl_xor(acc[j], off, 64);
    if (lane == 0) {
        int i = m & (nseg - 1);
        int b = m >> lns;
        float2 p0 = pred_point(pred0, ptPrev, nsegP, b, i);
        float2 p1 = pred_point(pred0, ptPrev, nsegP, b, i + 1);
        float cx = 0.5f * (p0.x + p1.x), cy = 0.5f * (p0.y + p1.y);
        float dx = 0.5f * (p1.x - p0.x), dy = 0.5f * (p1.y - p0.y);
        float f[6];
        #pragma unroll
        for (int j = 0; j < 6; ++j) f[j] = acc[j] + b3[j];
        f[0] -= 1.f;
        f[4] += 1.f;
        int npnt = nseg * 3;
        size_t base = ((size_t)b * npnt + 3 * i) * 2;
        #pragma unroll
        for (int s = 0; s < 3; ++s) {
            float px = f[2 * s], py = f[2 * s + 1];
            pt[base + 2 * s]     = dx * px - dy * py + cx;
            pt[base + 2 * s + 1] = dy * px + dx * py + cy;
        }
    }
}

// ---------------- final pair gather -> d_out (*6, drop last) ----------------
__global__ __launch_bounds__(256) void pairs_final_kernel(
    const float* __restrict__ pt, float* __restrict__ outp, int nsegP)
{
    int npnt = nsegP * 3;
    int Pn = 2 * nsegP + 1;
    int idx = blockIdx.x * 256 + threadIdx.x;
    int total = 32 * Pn * 2;
    if (idx >= total) return;
    int c = idx & 1;
    int t = idx >> 1;
    int p = t % Pn, b = t / Pn;
    int i1, i2; pair_idx(p, Pn, npnt, i1, i2);
    float v = 0.5f * (pt[((size_t)b * npnt + i1) * 2 + c] +
                      pt[((size_t)b * npnt + i2) * 2 + c]);
    if (p < Pn - 1) outp[((size_t)b * (Pn - 1) + p) * 2 + c] = 6.f * v;
}

// ---------------- launch ----------------
extern "C" void kernel_launch(void* const* d_in, const int* in_sizes, int n_in,
                              void* d_out, int out_size, void* d_ws, size_t ws_size,
                              hipStream_t stream) {
    (void)in_sizes; (void)n_in; (void)out_size; (void)ws_size;
    const float* feats[3] = {(const float*)d_in[1], (const float*)d_in[2], (const float*)d_in[3]};

    char* ws = (char*)d_ws;
    float* predA = (float*)(ws + OFF_PRED);
    float* ptA   = (float*)(ws + OFF_PTA);
    float* ptB   = (float*)(ws + OFF_PTB);
    __hip_bfloat16* f1 = (__hip_bfloat16*)(ws + OFF_F1);
    float* P2          = (float*)(ws + OFF_P2);
    __hip_bfloat16* xb = (__hip_bfloat16*)(ws + OFF_X);
    float* P1          = (float*)(ws + OFF_P1);

    const int Ks[3]  = {25088, 12544, 6272};
    const int S1s[3] = {28, 14, 7};          // slice = 896 everywhere
    const int lcs[3] = {9, 8, 7};
    const int Hs[3]  = {28, 56, 112};
    const int lnss[3] = {3, 4, 5};

    SetupArgs sa;
    size_t w1off = 0;
    for (int h = 0; h < 3; ++h) {
        sa.W1s[h] = (const float*)d_in[6 + 6 * h];
        sa.W1T[h] = (__hip_bfloat16*)(ws + OFF_W1T + w1off);
        sa.K[h]   = Ks[h];
        w1off += (size_t)Ks[h] * 1024 * 2;
        sa.W2s[h] = (const float*)d_in[8 + 6 * h];
        sa.W2T[h] = (__hip_bfloat16*)(ws + OFF_W2T + (size_t)h * 524288);
    }
    sa.lf = (const float*)d_in[0];
    sa.Wt = (const float*)d_in[4];
    sa.bt = (const float*)d_in[5];
    sa.pred = predA;

    setup_kernel<<<dim3(44816), 256, 0, stream>>>(sa);

    float* pts[2] = {ptA, ptB};
    const float* ptPrev = nullptr;
    int nsegP = 0;
    for (int h = 0; h < 3; ++h) {
        int lns = lnss[h], nseg = 1 << lns, M = 32 * nseg;
        int K = Ks[h], S1 = S1s[h];
        const float* b1 = (const float*)d_in[7 + 6 * h];
        const float* b2 = (const float*)d_in[9 + 6 * h];
        const float* W3 = (const float*)d_in[10 + 6 * h];
        const float* b3 = (const float*)d_in[11 + 6 * h];

        sample_kernel<<<dim3(32 * nseg), 256, 0, stream>>>(
            feats[h], Hs[h], lcs[h], predA, ptPrev, nsegP, lns, xb);

        gemm_mfma4<<<dim3(M / 64, 4, S1), 256, 0, stream>>>(
            xb, sa.W1T[h], P1, M, 1024, K, K / S1);

        reduce_tanh_kernel<<<dim3(M * 1024 / 256), 256, 0, stream>>>(P1, b1, f1, M, S1);

        gemm_mfma4<<<dim3(M / 64, 1, 8), 256, 0, stream>>>(
            f1, sa.W2T[h], P2, M, 256, 1024, 128);

        float* ptCur = pts[h & 1];
        gemm3pts_kernel<<<dim3(M), 64, 0, stream>>>(
            P2, b2, W3, b3, predA, ptPrev, nsegP, ptCur, lns, M);

        ptPrev = ptCur; nsegP = nseg;
    }

    pairs_final_kernel<<<dim3((32 * 65 * 2 + 255) / 256), 256, 0, stream>>>(
        ptA, (float*)d_out, 32);
}